// Round 12
// baseline (314.354 us; speedup 1.0000x reference)
//
#include <hip/hip_runtime.h>
#include <hip/hip_bf16.h>

#define B_ 16
#define N_ 4096
#define S_ 1024
#define K_ 32
#define D_ 64
#define M_ (B_*S_*K_)            // 524288 rows
#define EPS_ 1e-5f

#define OUT_NRM  (B_*S_*3)       // 49152
#define OUT_FEAT (2*B_*S_*3)     // 98304
#define OUT_FPS  (OUT_FEAT + B_*S_*128)  // 2195456

typedef __attribute__((ext_vector_type(8))) short bf16x8;
typedef __attribute__((ext_vector_type(4))) float f32x4;
typedef unsigned long long u64;

__device__ __forceinline__ unsigned short rnb(float x){
  return (unsigned short)((__float_as_uint(x) + 0x8000u) >> 16);
}
__device__ __forceinline__ void split1(float x, short& h, short& l){
  unsigned ux = __float_as_uint(x);
  unsigned uh = (ux + 0x8000u) & 0xFFFF0000u;
  h = (short)(uh >> 16);
  float lo = x - __uint_as_float(uh);
  l = (short)((__float_as_uint(lo) + 0x8000u) >> 16);
}
__device__ __forceinline__ unsigned f2key(float d){
  unsigned u = __float_as_uint(d);
  return u ^ ((unsigned)(((int)u) >> 31) | 0x80000000u);
}
__device__ __forceinline__ unsigned mprefix(u64 m){
  return __builtin_amdgcn_mbcnt_hi((unsigned)(m >> 32),
         __builtin_amdgcn_mbcnt_lo((unsigned)m, 0u));
}

// reduce 4 values across 16 lr-lanes; lane with bits(3,2)=(b3,b2) holds total of v[2*b3+b2]
__device__ __forceinline__ float hred4_sum(const float v[4], int l){
  bool hi8 = (l & 8) != 0;
  float send0 = hi8 ? v[0] : v[2];
  float send1 = hi8 ? v[1] : v[3];
  float r0 = __shfl_xor(send0, 8);
  float r1 = __shfl_xor(send1, 8);
  float a0 = (hi8 ? v[2] : v[0]) + r0;
  float a1 = (hi8 ? v[3] : v[1]) + r1;
  bool hi4 = (l & 4) != 0;
  float send = hi4 ? a0 : a1;
  float r = __shfl_xor(send, 4);
  float a = (hi4 ? a1 : a0) + r;
  a += __shfl_xor(a, 2);
  a += __shfl_xor(a, 1);
  return a;
}
__device__ __forceinline__ float hred4_max(const float v[4], int l){
  bool hi8 = (l & 8) != 0;
  float send0 = hi8 ? v[0] : v[2];
  float send1 = hi8 ? v[1] : v[3];
  float r0 = __shfl_xor(send0, 8);
  float r1 = __shfl_xor(send1, 8);
  float a0 = fmaxf(hi8 ? v[2] : v[0], r0);
  float a1 = fmaxf(hi8 ? v[3] : v[1], r1);
  bool hi4 = (l & 4) != 0;
  float send = hi4 ? a0 : a1;
  float r = __shfl_xor(send, 4);
  float a = fmaxf(hi4 ? a1 : a0, r);
  a = fmaxf(a, __shfl_xor(a, 2));
  a = fmaxf(a, __shfl_xor(a, 1));
  return a;
}

__global__ void zero_stats_kernel(float* __restrict__ stats){
  int t = blockIdx.x*256 + threadIdx.x;
  stats[t] = 0.f;
}

__global__ void meta_kernel(const float* __restrict__ xyz, const float* __restrict__ nrm,
                            const int* __restrict__ fps, float* __restrict__ out){
  int t = blockIdx.x*256 + threadIdx.x;
  if (t >= B_*S_) return;
  int b = t >> 10;
  int n = fps[t];
  const float* xp = xyz + ((size_t)b*N_ + n)*3;
  out[t*3+0] = xp[0]; out[t*3+1] = xp[1]; out[t*3+2] = xp[2];
  const float* pp = nrm + ((size_t)b*N_ + n)*3;
  out[OUT_NRM + t*3+0] = pp[0]; out[OUT_NRM + t*3+1] = pp[1]; out[OUT_NRM + t*3+2] = pp[2];
  out[OUT_FPS + t] = (float)n;
}

__global__ void packw_kernel(const float* __restrict__ w0, const float* __restrict__ w1,
                             const float* __restrict__ w2, unsigned short* __restrict__ dst){
  int e = blockIdx.x*256 + threadIdx.x;
  if (e >= 16384) return;
  const float* W; int base;
  if (e < 4096){ W = w0; base = 0; }
  else if (e < 8192){ W = w1; base = 4096; }
  else { W = w2; base = 8192; }
  int r = e - base;
  int frag = r >> 9;
  int lane = (r >> 3) & 63;
  int j = r & 7;
  int cht = frag >> 1, ks = frag & 1;
  int m = lane & 15, quad = lane >> 4;
  int ch = cht*16 + m, k = ks*32 + quad*8 + j;
  dst[e] = rnb(W[ch*64 + k]);
}

// ---- KNN stage 1: per (query, half of 2048 points) exact top-32 candidates ----
// 8 queries/block (2/wave) x one half; LDS 35 KB -> 4 blocks/CU; no forced VGPR cap
__global__ __launch_bounds__(256, 2) void knn_half(const float* __restrict__ xyz,
                                                   const int* __restrict__ fps,
                                                   u64* __restrict__ cand){
  __shared__ float4 Lp[2048];                  // 32 KB {x,y,z,pp}
  __shared__ unsigned skey[4][2][64];          // 2 KB
  __shared__ unsigned short sidx[4][2][64];    // 1 KB
  __shared__ unsigned scnt[4][2];
  const int t = threadIdx.x, w = t >> 6, l = t & 63;
  const int qg = blockIdx.x >> 1;              // 2048 query groups of 8
  const int half = blockIdx.x & 1;
  const int batch = qg >> 7;                   // 128 groups per batch
  const float* gp = xyz + ((size_t)batch*N_ + half*2048)*3;
  #pragma unroll
  for (int k = 0; k < 8; k++){
    int p = k*256 + t;
    float px = gp[p*3], py = gp[p*3+1], pz = gp[p*3+2];
    float pp = __fadd_rn(__fadd_rn(__fmul_rn(px,px), __fmul_rn(py,py)), __fmul_rn(pz,pz));
    Lp[p] = make_float4(px, py, pz, pp);
  }
  __syncthreads();
  const int q0 = qg*8 + w*2;
  const int nq0 = fps[q0], nq1 = fps[q0+1];
  const float* qp0 = xyz + ((size_t)batch*N_ + nq0)*3;
  const float* qp1 = xyz + ((size_t)batch*N_ + nq1)*3;
  const float qx0 = qp0[0], qy0 = qp0[1], qz0 = qp0[2];
  const float qx1 = qp1[0], qy1 = qp1[1], qz1 = qp1[2];
  const float qq0 = __fadd_rn(__fadd_rn(__fmul_rn(qx0,qx0), __fmul_rn(qy0,qy0)), __fmul_rn(qz0,qz0));
  const float qq1 = __fadd_rn(__fadd_rn(__fmul_rn(qx1,qx1), __fmul_rn(qy1,qy1)), __fmul_rn(qz1,qz1));
  float dv0[32], dv1[32];
  float vmin0 = 3.0e38f, vmin1 = 3.0e38f;
  #pragma unroll
  for (int i = 0; i < 32; i++){
    float4 p = Lp[i*64 + l];
    float dt0 = __fadd_rn(__fadd_rn(__fmul_rn(qx0,p.x), __fmul_rn(qy0,p.y)), __fmul_rn(qz0,p.z));
    float d0  = __fsub_rn(__fadd_rn(qq0,p.w), __fmul_rn(2.f,dt0));
    dv0[i] = d0; vmin0 = fminf(vmin0, d0);
    float dt1 = __fadd_rn(__fadd_rn(__fmul_rn(qx1,p.x), __fmul_rn(qy1,p.y)), __fmul_rn(qz1,p.z));
    float d1  = __fsub_rn(__fadd_rn(qq1,p.w), __fmul_rn(2.f,dt1));
    dv1[i] = d1; vmin1 = fminf(vmin1, d1);
  }
  // upper bound on rank-31 of the 64 lane-minima (guarantees >=32 survivors)
  unsigned k0 = f2key(vmin0), k1 = f2key(vmin1);
  unsigned lo0 = 0, hi0 = 0xFFFFFFFFu, lo1 = 0, hi1 = 0xFFFFFFFFu;
  for (int it = 0; it < 24; ++it){
    unsigned mid0 = lo0 + ((hi0 - lo0) >> 1);
    unsigned mid1 = lo1 + ((hi1 - lo1) >> 1);
    u64 m0 = __ballot(k0 <= mid0);
    u64 m1 = __ballot(k1 <= mid1);
    if (__popcll(m0) > 31) hi0 = mid0; else lo0 = mid0 + 1;
    if (__popcll(m1) > 31) hi1 = mid1; else lo1 = mid1 + 1;
  }
  const unsigned T0 = hi0, T1 = hi1;
  skey[w][0][l] = 0xFFFFFFFFu; skey[w][1][l] = 0xFFFFFFFFu;
  sidx[w][0][l] = 0xFFFF;      sidx[w][1][l] = 0xFFFF;
  if (l == 0){ scnt[w][0] = 0; scnt[w][1] = 0; }
  #pragma unroll
  for (int i = 0; i < 32; i++){
    int n = i*64 + l;
    unsigned u0 = f2key(dv0[i]);
    if (u0 <= T0){
      unsigned pos = atomicAdd(&scnt[w][0], 1u);
      if (pos < 64){ skey[w][0][pos] = u0; sidx[w][0][pos] = (unsigned short)n; }
    }
    unsigned u1 = f2key(dv1[i]);
    if (u1 <= T1){
      unsigned pos = atomicAdd(&scnt[w][1], 1u);
      if (pos < 64){ skey[w][1][pos] = u1; sidx[w][1][pos] = (unsigned short)n; }
    }
  }
  const unsigned tot0 = scnt[w][0], tot1 = scnt[w][1];   // >= 32 guaranteed
  const u64 PMAX = (1ull << 44) - 1;
  const unsigned gbase = half*2048;
  // fused exact 32-smallest (key, globalIdx) among <=64 survivors per query
  u64 pr0, pr1;
  {
    unsigned sk0 = skey[w][0][l], si0 = sidx[w][0][l];
    unsigned gi0 = (si0 == 0xFFFF) ? 0xFFFu : ((gbase + si0) & 0xFFFu);
    pr0 = ((u64)sk0 << 12) | gi0;
    unsigned sk1 = skey[w][1][l], si1 = sidx[w][1][l];
    unsigned gi1 = (si1 == 0xFFFF) ? 0xFFFu : ((gbase + si1) & 0xFFFu);
    pr1 = ((u64)sk1 << 12) | gi1;
  }
  u64 plo0 = 0, phi0 = PMAX, plo1 = 0, phi1 = PMAX;
  for (int it = 0; it < 44; ++it){
    u64 mid0 = plo0 + ((phi0 - plo0) >> 1);
    u64 mid1 = plo1 + ((phi1 - plo1) >> 1);
    int c0 = __popcll(__ballot(pr0 <= mid0));
    int c1 = __popcll(__ballot(pr1 <= mid1));
    if (c0 >= 32) phi0 = mid0; else plo0 = mid0 + 1;
    if (c1 >= 32) phi1 = mid1; else plo1 = mid1 + 1;
  }
  {
    bool sel = (pr0 <= plo0);
    u64 m = __ballot(sel);
    size_t cb = ((size_t)q0*2 + half)*32;
    if (sel) cand[cb + mprefix(m)] = pr0;
  }
  {
    bool sel = (pr1 <= plo1);
    u64 m = __ballot(sel);
    size_t cb = ((size_t)(q0+1)*2 + half)*32;
    if (sel) cand[cb + mprefix(m)] = pr1;
  }
  // rare fallback (survivors > 64): exact bisection over register dv[]
  #pragma unroll 1
  for (int qi = 0; qi < 2; qi++){
    unsigned tot = qi ? tot1 : tot0;
    if (tot <= 64) continue;
    u64 lo = 0, hi = PMAX;
    for (int it = 0; it < 44; ++it){
      u64 mid = lo + ((hi - lo) >> 1);
      int cc = 0;
      #pragma unroll
      for (int i = 0; i < 32; i++){
        float d = qi ? dv1[i] : dv0[i];
        u64 pr = ((u64)f2key(d) << 12) | (unsigned)(gbase + i*64 + l);
        cc += (pr <= mid) ? 1 : 0;
      }
      #pragma unroll
      for (int o2 = 32; o2 > 0; o2 >>= 1) cc += __shfl_xor(cc, o2);
      if (cc >= 32) hi = mid; else lo = mid + 1;
    }
    if (l == 0) scnt[w][qi] = 0;
    size_t cb = ((size_t)(q0+qi)*2 + half)*32;
    #pragma unroll
    for (int i = 0; i < 32; i++){
      float d = qi ? dv1[i] : dv0[i];
      u64 pr = ((u64)f2key(d) << 12) | (unsigned)(gbase + i*64 + l);
      if (pr <= lo){
        unsigned pos = atomicAdd(&scnt[w][qi], 1u);
        cand[cb + pos] = pr;    // exactly 32
      }
    }
  }
}

// ---- KNN stage 2: merge two half-candidate sets (64) -> exact global top-32 ----
__global__ __launch_bounds__(256, 8) void knn_merge(const u64* __restrict__ cand,
                                                    int* __restrict__ idxout){
  const int t = threadIdx.x, w = t >> 6, l = t & 63;
  const int q0 = blockIdx.x*8 + w*2;
  const u64 PMAX = (1ull << 44) - 1;
  u64 pA = cand[(size_t)q0*64 + l];
  u64 pB = cand[(size_t)(q0+1)*64 + l];
  u64 loA = 0, hiA = PMAX, loB = 0, hiB = PMAX;
  for (int it = 0; it < 44; ++it){
    u64 midA = loA + ((hiA - loA) >> 1);
    u64 midB = loB + ((hiB - loB) >> 1);
    int cA = __popcll(__ballot(pA <= midA));
    int cB = __popcll(__ballot(pB <= midB));
    if (cA >= 32) hiA = midA; else loA = midA + 1;
    if (cB >= 32) hiB = midB; else loB = midB + 1;
  }
  {
    bool sel = (pA <= loA);
    u64 m = __ballot(sel);
    if (sel) idxout[(size_t)q0*K_ + mprefix(m)] = (int)(pA & 0xFFFull);
  }
  {
    bool sel = (pB <= loB);
    u64 m = __ballot(sel);
    if (sel) idxout[(size_t)(q0+1)*K_ + mprefix(m)] = (int)(pB & 0xFFFull);
  }
}

// ---- conv1: gather -> split-MFMA -> Y1 + stats. 64 rows/wave, grid 2048 ----
__global__ __launch_bounds__(256, 2) void conv1_mfma(const float* __restrict__ pts,
    const int* __restrict__ idx, const unsigned short* __restrict__ wpk,
    const float* __restrict__ bias, unsigned short* __restrict__ Yo,
    float* __restrict__ stats){
  __shared__ float sred[4][128];
  const int t = threadIdx.x, w = t>>6, l = t&63, quad = l>>4, lr = l&15;
  const int m0 = blockIdx.x*256;
  const int Rw = m0 + w*64;
  const int b = m0 >> 15;
  bf16x8 wf[4][2];
  #pragma unroll
  for (int c = 0; c < 4; c++)
    #pragma unroll
    for (int s = 0; s < 2; s++)
      wf[c][s] = *(const bf16x8*)(wpk + (((c*2+s)<<6) + l)*8);
  f32x4 acc[4][4];
  #pragma unroll
  for (int c = 0; c < 4; c++)
    #pragma unroll
    for (int rt = 0; rt < 4; rt++)
      acc[c][rt] = (f32x4){0.f,0.f,0.f,0.f};
  int ri[4];
  #pragma unroll
  for (int rt = 0; rt < 4; rt++) ri[rt] = idx[Rw + rt*16 + lr];
  #pragma unroll
  for (int s = 0; s < 2; s++){
    #pragma unroll
    for (int rt = 0; rt < 4; rt++){
      const float* pr = pts + ((size_t)(b*4096 + ri[rt]))*64;
      float4 v0 = *(const float4*)(pr + s*32 + quad*8);
      float4 v1 = *(const float4*)(pr + s*32 + quad*8 + 4);
      float xs[8] = {v0.x,v0.y,v0.z,v0.w,v1.x,v1.y,v1.z,v1.w};
      bf16x8 xh, xl;
      #pragma unroll
      for (int j = 0; j < 8; j++){ short hh, ll; split1(xs[j], hh, ll); xh[j]=hh; xl[j]=ll; }
      #pragma unroll
      for (int c = 0; c < 4; c++){
        acc[c][rt] = __builtin_amdgcn_mfma_f32_16x16x32_bf16(wf[c][s], xh, acc[c][rt], 0,0,0);
        acc[c][rt] = __builtin_amdgcn_mfma_f32_16x16x32_bf16(wf[c][s], xl, acc[c][rt], 0,0,0);
      }
    }
  }
  const int rtg0 = Rw >> 4;
  #pragma unroll
  for (int c = 0; c < 4; c++){
    float4 bq = *(const float4*)(bias + c*16 + quad*4);
    float bqa[4] = {bq.x, bq.y, bq.z, bq.w};
    float sv[4] = {0,0,0,0}, qv[4] = {0,0,0,0};
    int kb = c*2 + (quad>>1);
    int sub = (quad&1)*4;
    #pragma unroll
    for (int rt = 0; rt < 4; rt++){
      float y[4];
      #pragma unroll
      for (int r = 0; r < 4; r++){
        y[r] = acc[c][rt][r] + bqa[r];
        sv[r] += y[r];
        qv[r] += y[r]*y[r];
      }
      uint2 p;
      p.x = (unsigned)rnb(y[0]) | ((unsigned)rnb(y[1])<<16);
      p.y = (unsigned)rnb(y[2]) | ((unsigned)rnb(y[3])<<16);
      *(uint2*)(Yo + ((((rtg0+rt)*8 + kb)*16 + lr)*8 + sub)) = p;
    }
    float S = hred4_sum(sv, l);
    float Q = hred4_sum(qv, l);
    if ((l & 3) == 0){
      int ch = c*16 + quad*4 + ((l>>3)&1)*2 + ((l>>2)&1);
      sred[w][ch] = S;
      sred[w][64 + ch] = Q;
    }
  }
  __syncthreads();
  if (t < 128){
    float tot = sred[0][t]+sred[1][t]+sred[2][t]+sred[3][t];
    unsafeAtomicAdd(&stats[(blockIdx.x & 7)*512 + t], tot);
  }
}

// ---- conv2: Y1 -> affine+relu -> MFMA (no split) -> Y2 + stats. 64 rows/wave ----
__global__ __launch_bounds__(256, 2) void conv2_mfma(const unsigned short* __restrict__ Yi,
    const unsigned short* __restrict__ wpk, const float* __restrict__ bias,
    const float* __restrict__ aff, unsigned short* __restrict__ Yo,
    float* __restrict__ stats){
  __shared__ float sred[4][128];
  const int t = threadIdx.x, w = t>>6, l = t&63, quad = l>>4, lr = l&15;
  const int m0 = blockIdx.x*256;
  const int Rw = m0 + w*64;
  bf16x8 wf[4][2];
  #pragma unroll
  for (int c = 0; c < 4; c++)
    #pragma unroll
    for (int s = 0; s < 2; s++)
      wf[c][s] = *(const bf16x8*)(wpk + (((c*2+s)<<6) + l)*8);
  f32x4 acc[4][4];
  #pragma unroll
  for (int c = 0; c < 4; c++)
    #pragma unroll
    for (int rt = 0; rt < 4; rt++)
      acc[c][rt] = (f32x4){0.f,0.f,0.f,0.f};
  const int rtg0 = Rw >> 4;
  #pragma unroll
  for (int s = 0; s < 2; s++){
    float4 A0 = *(const float4*)(aff + s*32 + quad*8);
    float4 A1 = *(const float4*)(aff + s*32 + quad*8 + 4);
    float4 B0 = *(const float4*)(aff + 64 + s*32 + quad*8);
    float4 B1 = *(const float4*)(aff + 64 + s*32 + quad*8 + 4);
    float aA[8] = {A0.x,A0.y,A0.z,A0.w,A1.x,A1.y,A1.z,A1.w};
    float aB[8] = {B0.x,B0.y,B0.z,B0.w,B1.x,B1.y,B1.z,B1.w};
    #pragma unroll
    for (int rt = 0; rt < 4; rt++){
      uint4 u = *(const uint4*)(Yi + (((rtg0+rt)*8 + s*4 + quad)*16 + lr)*8);
      unsigned ua[4] = {u.x,u.y,u.z,u.w};
      bf16x8 xb;
      #pragma unroll
      for (int j = 0; j < 8; j++){
        unsigned wd = ua[j>>1];
        float yf = __uint_as_float((j&1) ? (wd & 0xFFFF0000u) : (wd << 16));
        float x = fmaxf(0.f, fmaf(yf, aA[j], aB[j]));
        xb[j] = (short)rnb(x);
      }
      #pragma unroll
      for (int c = 0; c < 4; c++)
        acc[c][rt] = __builtin_amdgcn_mfma_f32_16x16x32_bf16(wf[c][s], xb, acc[c][rt], 0,0,0);
    }
  }
  #pragma unroll
  for (int c = 0; c < 4; c++){
    float4 bq = *(const float4*)(bias + c*16 + quad*4);
    float bqa[4] = {bq.x, bq.y, bq.z, bq.w};
    float sv[4] = {0,0,0,0}, qv[4] = {0,0,0,0};
    int kb = c*2 + (quad>>1);
    int sub = (quad&1)*4;
    #pragma unroll
    for (int rt = 0; rt < 4; rt++){
      float y[4];
      #pragma unroll
      for (int r = 0; r < 4; r++){
        y[r] = acc[c][rt][r] + bqa[r];
        sv[r] += y[r];
        qv[r] += y[r]*y[r];
      }
      uint2 p;
      p.x = (unsigned)rnb(y[0]) | ((unsigned)rnb(y[1])<<16);
      p.y = (unsigned)rnb(y[2]) | ((unsigned)rnb(y[3])<<16);
      *(uint2*)(Yo + ((((rtg0+rt)*8 + kb)*16 + lr)*8 + sub)) = p;
    }
    float S = hred4_sum(sv, l);
    float Q = hred4_sum(qv, l);
    if ((l & 3) == 0){
      int ch = c*16 + quad*4 + ((l>>3)&1)*2 + ((l>>2)&1);
      sred[w][ch] = S;
      sred[w][64 + ch] = Q;
    }
  }
  __syncthreads();
  if (t < 128){
    float tot = sred[0][t]+sred[1][t]+sred[2][t]+sred[3][t];
    unsafeAtomicAdd(&stats[(blockIdx.x & 7)*512 + 128 + t], tot);
  }
}

// ---- conv3: Y2 -> affine+relu -> MFMA (no split) -> K-maxpool + stats. 32 rows/wave ----
__global__ __launch_bounds__(256, 2) void conv3_mfma(const unsigned short* __restrict__ Yi,
    const unsigned short* __restrict__ wpk, const float* __restrict__ bias,
    const float* __restrict__ aff, float* __restrict__ ymax,
    float* __restrict__ stats){
  __shared__ float sred[4][256];
  const int t = threadIdx.x, w = t>>6, l = t&63, quad = l>>4, lr = l&15;
  const int m0 = blockIdx.x*128;
  const int Rw = m0 + w*32;
  bf16x8 wf[8][2];
  #pragma unroll
  for (int c = 0; c < 8; c++)
    #pragma unroll
    for (int s = 0; s < 2; s++)
      wf[c][s] = *(const bf16x8*)(wpk + (((c*2+s)<<6) + l)*8);
  f32x4 acc[8][2];
  #pragma unroll
  for (int c = 0; c < 8; c++){
    acc[c][0] = (f32x4){0.f,0.f,0.f,0.f};
    acc[c][1] = (f32x4){0.f,0.f,0.f,0.f};
  }
  const int rtg0 = Rw >> 4;
  #pragma unroll
  for (int s = 0; s < 2; s++){
    float4 A0 = *(const float4*)(aff + s*32 + quad*8);
    float4 A1 = *(const float4*)(aff + s*32 + quad*8 + 4);
    float4 B0 = *(const float4*)(aff + 64 + s*32 + quad*8);
    float4 B1 = *(const float4*)(aff + 64 + s*32 + quad*8 + 4);
    float aA[8] = {A0.x,A0.y,A0.z,A0.w,A1.x,A1.y,A1.z,A1.w};
    float aB[8] = {B0.x,B0.y,B0.z,B0.w,B1.x,B1.y,B1.z,B1.w};
    #pragma unroll
    for (int rt = 0; rt < 2; rt++){
      uint4 u = *(const uint4*)(Yi + (((rtg0+rt)*8 + s*4 + quad)*16 + lr)*8);
      unsigned ua[4] = {u.x,u.y,u.z,u.w};
      bf16x8 xb;
      #pragma unroll
      for (int j = 0; j < 8; j++){
        unsigned wd = ua[j>>1];
        float yf = __uint_as_float((j&1) ? (wd & 0xFFFF0000u) : (wd << 16));
        float x = fmaxf(0.f, fmaf(yf, aA[j], aB[j]));
        xb[j] = (short)rnb(x);
      }
      #pragma unroll
      for (int c = 0; c < 8; c++)
        acc[c][rt] = __builtin_amdgcn_mfma_f32_16x16x32_bf16(wf[c][s], xb, acc[c][rt], 0,0,0);
    }
  }
  const int g = Rw >> 5;
  #pragma unroll
  for (int c = 0; c < 8; c++){
    float4 bq = *(const float4*)(bias + c*16 + quad*4);
    float bqa[4] = {bq.x, bq.y, bq.z, bq.w};
    float sv[4], qv[4], mv[4];
    #pragma unroll
    for (int r = 0; r < 4; r++){
      float y0 = acc[c][0][r] + bqa[r];
      float y1 = acc[c][1][r] + bqa[r];
      sv[r] = y0 + y1;
      qv[r] = y0*y0 + y1*y1;
      mv[r] = fmaxf(y0, y1);
    }
    float S = hred4_sum(sv, l);
    float Q = hred4_sum(qv, l);
    float Mx = hred4_max(mv, l);
    if ((l & 3) == 0){
      int ch = c*16 + quad*4 + ((l>>3)&1)*2 + ((l>>2)&1);
      sred[w][ch] = S;
      sred[w][128 + ch] = Q;
      ymax[(size_t)g*128 + ch] = Mx;
    }
  }
  __syncthreads();
  {
    float tot = sred[0][t]+sred[1][t]+sred[2][t]+sred[3][t];
    unsafeAtomicAdd(&stats[(blockIdx.x & 7)*512 + 256 + t], tot);
  }
}

__global__ void bnparam_kernel(const float* __restrict__ stats, const float* __restrict__ g,
                               const float* __restrict__ bt, float* __restrict__ outAS,
                               int sOff, int qOff, int C){
  int c = threadIdx.x;
  if (c >= C) return;
  const float inv = 1.f/(float)M_;
  float S = 0.f, Q = 0.f;
  #pragma unroll
  for (int r = 0; r < 8; r++){
    S += stats[r*512 + sOff + c];
    Q += stats[r*512 + qOff + c];
  }
  float mean = S * inv;
  float var  = Q * inv - mean*mean;
  float a = g[c] * rsqrtf(var + EPS_);
  outAS[c] = a;
  outAS[C + c] = bt[c] - mean*a;
}

__global__ void final_kernel(const float* __restrict__ ymax,
                             const float* __restrict__ affb, float* __restrict__ out){
  int t = blockIdx.x*256 + threadIdx.x;
  int o = t & 127;
  float a = affb[256 + o], s = affb[384 + o];
  out[OUT_FEAT + t] = fmaxf(0.f, a*ymax[t] + s);
}

extern "C" void kernel_launch(void* const* d_in, const int* in_sizes, int n_in,
                              void* d_out, int out_size, void* d_ws, size_t ws_size,
                              hipStream_t stream) {
  const float* xyz = (const float*)d_in[0];
  const float* nrm = (const float*)d_in[1];
  const float* pts = (const float*)d_in[2];
  const int*   fps = (const int*)d_in[3];
  const float* w0  = (const float*)d_in[4];
  const float* b0  = (const float*)d_in[5];
  const float* g0  = (const float*)d_in[6];
  const float* bt0 = (const float*)d_in[7];
  const float* w1  = (const float*)d_in[8];
  const float* b1  = (const float*)d_in[9];
  const float* g1  = (const float*)d_in[10];
  const float* bt1 = (const float*)d_in[11];
  const float* w2  = (const float*)d_in[12];
  const float* b2  = (const float*)d_in[13];
  const float* g2  = (const float*)d_in[14];
  const float* bt2 = (const float*)d_in[15];
  float* out = (float*)d_out;

  char* ws = (char*)d_ws;
  float* stats = (float*)ws;                                  // 16 KB
  float* affb  = (float*)(ws + 16384);                        // 2 KB
  int*   idxb  = (int*)(ws + 20480);                          // 2 MB
  float* ymax  = (float*)(ws + 2117632);                      // 8 MB
  unsigned short* wpack = (unsigned short*)(ws + 11554816);   // 32 KB
  unsigned short* Y1 = (unsigned short*)(ws + 18878464);      // 64 MB
  unsigned short* Y2 = (unsigned short*)(ws + 85987328);      // 64 MB
  u64* cand = (u64*)(ws + 18878464);                          // 8 MB, overlaps Y1 (dead until conv1)

  zero_stats_kernel<<<16, 256, 0, stream>>>(stats);
  meta_kernel<<<64, 256, 0, stream>>>(xyz, nrm, fps, out);
  packw_kernel<<<64, 256, 0, stream>>>(w0, w1, w2, wpack);
  knn_half<<<4096, 256, 0, stream>>>(xyz, fps, cand);
  knn_merge<<<2048, 256, 0, stream>>>(cand, idxb);
  conv1_mfma<<<2048, 256, 0, stream>>>(pts, idxb, wpack, b0, Y1, stats);
  bnparam_kernel<<<1, 64, 0, stream>>>(stats, g0, bt0, affb, 0, 64, 64);
  conv2_mfma<<<2048, 256, 0, stream>>>(Y1, wpack + 4096, b1, affb, Y2, stats);
  bnparam_kernel<<<1, 64, 0, stream>>>(stats, g1, bt1, affb + 128, 128, 192, 64);
  conv3_mfma<<<4096, 256, 0, stream>>>(Y2, wpack + 8192, b2, affb + 128, ymax, stats);
  bnparam_kernel<<<1, 128, 0, stream>>>(stats, g2, bt2, affb + 256, 256, 384, 128);
  final_kernel<<<8192, 256, 0, stream>>>(ymax, affb, out);
}

// Round 13
// 291.687 us; speedup vs baseline: 1.0777x; 1.0777x over previous
//
#include <hip/hip_runtime.h>
#include <hip/hip_bf16.h>

#define B_ 16
#define N_ 4096
#define S_ 1024
#define K_ 32
#define D_ 64
#define M_ (B_*S_*K_)            // 524288 rows
#define EPS_ 1e-5f

#define OUT_NRM  (B_*S_*3)       // 49152
#define OUT_FEAT (2*B_*S_*3)     // 98304
#define OUT_FPS  (OUT_FEAT + B_*S_*128)  // 2195456

typedef __attribute__((ext_vector_type(8))) short bf16x8;
typedef __attribute__((ext_vector_type(4))) float f32x4;
typedef unsigned long long u64;

__device__ __forceinline__ unsigned short rnb(float x){
  return (unsigned short)((__float_as_uint(x) + 0x8000u) >> 16);
}
__device__ __forceinline__ void split1(float x, short& h, short& l){
  unsigned ux = __float_as_uint(x);
  unsigned uh = (ux + 0x8000u) & 0xFFFF0000u;
  h = (short)(uh >> 16);
  float lo = x - __uint_as_float(uh);
  l = (short)((__float_as_uint(lo) + 0x8000u) >> 16);
}
__device__ __forceinline__ unsigned f2key(float d){
  unsigned u = __float_as_uint(d);
  return u ^ ((unsigned)(((int)u) >> 31) | 0x80000000u);
}
__device__ __forceinline__ float key2f(unsigned u){
  unsigned v = (u & 0x80000000u) ? (u ^ 0x80000000u) : ~u;
  return __uint_as_float(v);
}
__device__ __forceinline__ unsigned mprefix(u64 m){
  return __builtin_amdgcn_mbcnt_hi((unsigned)(m >> 32),
         __builtin_amdgcn_mbcnt_lo((unsigned)m, 0u));
}

// reduce 4 values across 16 lr-lanes; lane with bits(3,2)=(b3,b2) holds total of v[2*b3+b2]
__device__ __forceinline__ float hred4_sum(const float v[4], int l){
  bool hi8 = (l & 8) != 0;
  float send0 = hi8 ? v[0] : v[2];
  float send1 = hi8 ? v[1] : v[3];
  float r0 = __shfl_xor(send0, 8);
  float r1 = __shfl_xor(send1, 8);
  float a0 = (hi8 ? v[2] : v[0]) + r0;
  float a1 = (hi8 ? v[3] : v[1]) + r1;
  bool hi4 = (l & 4) != 0;
  float send = hi4 ? a0 : a1;
  float r = __shfl_xor(send, 4);
  float a = (hi4 ? a1 : a0) + r;
  a += __shfl_xor(a, 2);
  a += __shfl_xor(a, 1);
  return a;
}
__device__ __forceinline__ float hred4_max(const float v[4], int l){
  bool hi8 = (l & 8) != 0;
  float send0 = hi8 ? v[0] : v[2];
  float send1 = hi8 ? v[1] : v[3];
  float r0 = __shfl_xor(send0, 8);
  float r1 = __shfl_xor(send1, 8);
  float a0 = fmaxf(hi8 ? v[2] : v[0], r0);
  float a1 = fmaxf(hi8 ? v[3] : v[1], r1);
  bool hi4 = (l & 4) != 0;
  float send = hi4 ? a0 : a1;
  float r = __shfl_xor(send, 4);
  float a = fmaxf(hi4 ? a1 : a0, r);
  a = fmaxf(a, __shfl_xor(a, 2));
  a = fmaxf(a, __shfl_xor(a, 1));
  return a;
}

__global__ void zero_stats_kernel(float* __restrict__ stats){
  int t = blockIdx.x*256 + threadIdx.x;
  stats[t] = 0.f;
}

__global__ void meta_kernel(const float* __restrict__ xyz, const float* __restrict__ nrm,
                            const int* __restrict__ fps, float* __restrict__ out){
  int t = blockIdx.x*256 + threadIdx.x;
  if (t >= B_*S_) return;
  int b = t >> 10;
  int n = fps[t];
  const float* xp = xyz + ((size_t)b*N_ + n)*3;
  out[t*3+0] = xp[0]; out[t*3+1] = xp[1]; out[t*3+2] = xp[2];
  const float* pp = nrm + ((size_t)b*N_ + n)*3;
  out[OUT_NRM + t*3+0] = pp[0]; out[OUT_NRM + t*3+1] = pp[1]; out[OUT_NRM + t*3+2] = pp[2];
  out[OUT_FPS + t] = (float)n;
}

__global__ void packw_kernel(const float* __restrict__ w0, const float* __restrict__ w1,
                             const float* __restrict__ w2, unsigned short* __restrict__ dst){
  int e = blockIdx.x*256 + threadIdx.x;
  if (e >= 16384) return;
  const float* W; int base;
  if (e < 4096){ W = w0; base = 0; }
  else if (e < 8192){ W = w1; base = 4096; }
  else { W = w2; base = 8192; }
  int r = e - base;
  int frag = r >> 9;
  int lane = (r >> 3) & 63;
  int j = r & 7;
  int cht = frag >> 1, ks = frag & 1;
  int m = lane & 15, quad = lane >> 4;
  int ch = cht*16 + m, k = ks*32 + quad*8 + j;
  dst[e] = rnb(W[ch*64 + k]);
}

// ---- KNN: monolithic champion (R11): LDS-staged xyz, 2 q/wave, ballot selection ----
__global__ __launch_bounds__(256, 2) void knn_kernel(const float* __restrict__ xyz,
                                                     const int* __restrict__ fps,
                                                     int* __restrict__ idxout){
  __shared__ float Lx[N_*3];                   // 48 KB
  __shared__ unsigned skey[4][2][64];          // 2 KB
  __shared__ unsigned short sidx[4][2][64];    // 1 KB
  __shared__ unsigned scnt[4][2];
  const int t = threadIdx.x, w = t >> 6, l = t & 63;
  const int b = blockIdx.x >> 7;        // 128 blocks per batch
  {
    const float4* src = (const float4*)(xyz + (size_t)b*(N_*3));
    float4* dst = (float4*)Lx;
    #pragma unroll
    for (int j = 0; j < 12; j++) dst[j*256 + t] = src[j*256 + t];
  }
  __syncthreads();
  const int q0 = blockIdx.x*8 + w*2;
  const int nq0 = fps[q0], nq1 = fps[q0+1];
  const float qx0 = Lx[nq0*3], qy0 = Lx[nq0*3+1], qz0 = Lx[nq0*3+2];
  const float qx1 = Lx[nq1*3], qy1 = Lx[nq1*3+1], qz1 = Lx[nq1*3+2];
  const float qq0 = __fadd_rn(__fadd_rn(__fmul_rn(qx0,qx0), __fmul_rn(qy0,qy0)), __fmul_rn(qz0,qz0));
  const float qq1 = __fadd_rn(__fadd_rn(__fmul_rn(qx1,qx1), __fmul_rn(qy1,qy1)), __fmul_rn(qz1,qz1));
  float dv0[64], dv1[64];
  float vmin0 = 3.0e38f, vmin1 = 3.0e38f;
  #pragma unroll
  for (int i = 0; i < 64; i++){
    const float* p = &Lx[(i*64 + l)*3];
    float px = p[0], py = p[1], pz = p[2];
    float pp = __fadd_rn(__fadd_rn(__fmul_rn(px,px), __fmul_rn(py,py)), __fmul_rn(pz,pz));
    float dt0 = __fadd_rn(__fadd_rn(__fmul_rn(qx0,px), __fmul_rn(qy0,py)), __fmul_rn(qz0,pz));
    float d0  = __fsub_rn(__fadd_rn(qq0,pp), __fmul_rn(2.f,dt0));
    dv0[i] = d0; vmin0 = fminf(vmin0, d0);
    float dt1 = __fadd_rn(__fadd_rn(__fmul_rn(qx1,px), __fmul_rn(qy1,py)), __fmul_rn(qz1,pz));
    float d1  = __fsub_rn(__fadd_rn(qq1,pp), __fmul_rn(2.f,dt1));
    dv1[i] = d1; vmin1 = fminf(vmin1, d1);
  }
  unsigned k0 = f2key(vmin0), k1 = f2key(vmin1);
  unsigned lo0 = 0, hi0 = 0xFFFFFFFFu, lo1 = 0, hi1 = 0xFFFFFFFFu;
  for (int it = 0; it < 32; ++it){
    unsigned mid0 = lo0 + ((hi0 - lo0) >> 1);
    unsigned mid1 = lo1 + ((hi1 - lo1) >> 1);
    u64 m0 = __ballot(k0 <= mid0);
    u64 m1 = __ballot(k1 <= mid1);
    if (__popcll(m0) > 31) hi0 = mid0; else lo0 = mid0 + 1;
    if (__popcll(m1) > 31) hi1 = mid1; else lo1 = mid1 + 1;
  }
  const float T0 = key2f(lo0), T1 = key2f(lo1);
  skey[w][0][l] = 0xFFFFFFFFu; skey[w][1][l] = 0xFFFFFFFFu;
  sidx[w][0][l] = 0xFFF;       sidx[w][1][l] = 0xFFF;
  if (l == 0){ scnt[w][0] = 0; scnt[w][1] = 0; }
  #pragma unroll
  for (int i = 0; i < 64; i++){
    int n = i*64 + l;
    float d0 = dv0[i];
    if (d0 <= T0){
      unsigned pos = atomicAdd(&scnt[w][0], 1u);
      if (pos < 64){ skey[w][0][pos] = f2key(d0); sidx[w][0][pos] = (unsigned short)n; }
    }
    float d1 = dv1[i];
    if (d1 <= T1){
      unsigned pos = atomicAdd(&scnt[w][1], 1u);
      if (pos < 64){ skey[w][1][pos] = f2key(d1); sidx[w][1][pos] = (unsigned short)n; }
    }
  }
  const unsigned tot0 = scnt[w][0], tot1 = scnt[w][1];   // >= 32 guaranteed

  {
    const size_t ob = (size_t)q0 * K_;
    if (tot0 <= 64){
      u64 pair = ((u64)skey[w][0][l] << 12) | (unsigned)sidx[w][0][l];
      u64 plo = 0, phi = (1ull << 44) - 1;
      for (int it = 0; it < 44; ++it){
        u64 mid = plo + ((phi - plo) >> 1);
        u64 m = __ballot(pair <= mid);
        if (__popcll(m) >= 32) phi = mid; else plo = mid + 1;
      }
      bool sel = (pair <= plo);
      u64 m = __ballot(sel);
      unsigned pos = mprefix(m);
      if (sel) idxout[ob + pos] = (int)(pair & 0xFFFull);
    } else {
      u64 lo = 0, hi = (1ull << 44) - 1;
      for (int it = 0; it < 44; ++it){
        u64 mid = (lo + hi) >> 1;
        unsigned midk = (unsigned)(mid >> 12);
        unsigned midi = (unsigned)(mid & 0xFFFull);
        int cc = 0;
        #pragma unroll
        for (int i = 0; i < 64; i++){
          unsigned u = f2key(dv0[i]);
          unsigned n = (unsigned)(i*64 + l);
          cc += (u < midk || (u == midk && n <= midi)) ? 1 : 0;
        }
        #pragma unroll
        for (int o2 = 32; o2 > 0; o2 >>= 1) cc += __shfl_xor(cc, o2);
        if (cc >= 32) hi = mid; else lo = mid + 1;
      }
      const unsigned Ck = (unsigned)(lo >> 12);
      const unsigned Ci = (unsigned)(lo & 0xFFFull);
      int c2 = 0;
      #pragma unroll
      for (int i = 0; i < 64; i++){
        unsigned u = f2key(dv0[i]);
        unsigned n = (unsigned)(i*64 + l);
        c2 += (u < Ck || (u == Ck && n <= Ci)) ? 1 : 0;
      }
      int inc2 = c2;
      #pragma unroll
      for (int off = 1; off < 64; off <<= 1){
        int t2 = __shfl_up(inc2, off);
        if (l >= off) inc2 += t2;
      }
      int off3 = inc2 - c2;
      #pragma unroll
      for (int i = 0; i < 64; i++){
        unsigned u = f2key(dv0[i]);
        unsigned n = (unsigned)(i*64 + l);
        if (u < Ck || (u == Ck && n <= Ci)){
          sidx[w][0][off3] = (unsigned short)n;
          off3++;
        }
      }
      if (l < 32) idxout[ob + l] = (int)sidx[w][0][l];
    }
  }
  {
    const size_t ob = (size_t)(q0+1) * K_;
    if (tot1 <= 64){
      u64 pair = ((u64)skey[w][1][l] << 12) | (unsigned)sidx[w][1][l];
      u64 plo = 0, phi = (1ull << 44) - 1;
      for (int it = 0; it < 44; ++it){
        u64 mid = plo + ((phi - plo) >> 1);
        u64 m = __ballot(pair <= mid);
        if (__popcll(m) >= 32) phi = mid; else plo = mid + 1;
      }
      bool sel = (pair <= plo);
      u64 m = __ballot(sel);
      unsigned pos = mprefix(m);
      if (sel) idxout[ob + pos] = (int)(pair & 0xFFFull);
    } else {
      u64 lo = 0, hi = (1ull << 44) - 1;
      for (int it = 0; it < 44; ++it){
        u64 mid = (lo + hi) >> 1;
        unsigned midk = (unsigned)(mid >> 12);
        unsigned midi = (unsigned)(mid & 0xFFFull);
        int cc = 0;
        #pragma unroll
        for (int i = 0; i < 64; i++){
          unsigned u = f2key(dv1[i]);
          unsigned n = (unsigned)(i*64 + l);
          cc += (u < midk || (u == midk && n <= midi)) ? 1 : 0;
        }
        #pragma unroll
        for (int o2 = 32; o2 > 0; o2 >>= 1) cc += __shfl_xor(cc, o2);
        if (cc >= 32) hi = mid; else lo = mid + 1;
      }
      const unsigned Ck = (unsigned)(lo >> 12);
      const unsigned Ci = (unsigned)(lo & 0xFFFull);
      int c2 = 0;
      #pragma unroll
      for (int i = 0; i < 64; i++){
        unsigned u = f2key(dv1[i]);
        unsigned n = (unsigned)(i*64 + l);
        c2 += (u < Ck || (u == Ck && n <= Ci)) ? 1 : 0;
      }
      int inc2 = c2;
      #pragma unroll
      for (int off = 1; off < 64; off <<= 1){
        int t2 = __shfl_up(inc2, off);
        if (l >= off) inc2 += t2;
      }
      int off3 = inc2 - c2;
      #pragma unroll
      for (int i = 0; i < 64; i++){
        unsigned u = f2key(dv1[i]);
        unsigned n = (unsigned)(i*64 + l);
        if (u < Ck || (u == Ck && n <= Ci)){
          sidx[w][1][off3] = (unsigned short)n;
          off3++;
        }
      }
      if (l < 32) idxout[ob + l] = (int)sidx[w][1][l];
    }
  }
}

// ---- conv1: gather -> split-MFMA -> Y1 + stats. W frags in LDS; 64 rows/wave ----
__global__ __launch_bounds__(256, 3) void conv1_mfma(const float* __restrict__ pts,
    const int* __restrict__ idx, const unsigned short* __restrict__ wpk,
    const float* __restrict__ bias, unsigned short* __restrict__ Yo,
    float* __restrict__ stats){
  __shared__ float sred[4][128];
  __shared__ uint4 Wl4[512];           // 8 KB packed W frags
  const unsigned short* Wl = (const unsigned short*)Wl4;
  const int t = threadIdx.x, w = t>>6, l = t&63, quad = l>>4, lr = l&15;
  const int m0 = blockIdx.x*256;
  const int Rw = m0 + w*64;
  const int b = m0 >> 15;
  Wl4[t] = ((const uint4*)wpk)[t];
  Wl4[256 + t] = ((const uint4*)wpk)[256 + t];
  f32x4 acc[4][4];
  #pragma unroll
  for (int c = 0; c < 4; c++)
    #pragma unroll
    for (int rt = 0; rt < 4; rt++)
      acc[c][rt] = (f32x4){0.f,0.f,0.f,0.f};
  int ri[4];
  #pragma unroll
  for (int rt = 0; rt < 4; rt++) ri[rt] = idx[Rw + rt*16 + lr];
  __syncthreads();
  #pragma unroll
  for (int s = 0; s < 2; s++){
    bf16x8 wfs[4];
    #pragma unroll
    for (int c = 0; c < 4; c++)
      wfs[c] = *(const bf16x8*)(Wl + (((c*2+s)<<6) + l)*8);
    #pragma unroll
    for (int rt = 0; rt < 4; rt++){
      const float* pr = pts + ((size_t)(b*4096 + ri[rt]))*64;
      float4 v0 = *(const float4*)(pr + s*32 + quad*8);
      float4 v1 = *(const float4*)(pr + s*32 + quad*8 + 4);
      float xs[8] = {v0.x,v0.y,v0.z,v0.w,v1.x,v1.y,v1.z,v1.w};
      bf16x8 xh, xl;
      #pragma unroll
      for (int j = 0; j < 8; j++){ short hh, ll; split1(xs[j], hh, ll); xh[j]=hh; xl[j]=ll; }
      #pragma unroll
      for (int c = 0; c < 4; c++){
        acc[c][rt] = __builtin_amdgcn_mfma_f32_16x16x32_bf16(wfs[c], xh, acc[c][rt], 0,0,0);
        acc[c][rt] = __builtin_amdgcn_mfma_f32_16x16x32_bf16(wfs[c], xl, acc[c][rt], 0,0,0);
      }
    }
  }
  const int rtg0 = Rw >> 4;
  #pragma unroll
  for (int c = 0; c < 4; c++){
    float4 bq = *(const float4*)(bias + c*16 + quad*4);
    float bqa[4] = {bq.x, bq.y, bq.z, bq.w};
    float sv[4] = {0,0,0,0}, qv[4] = {0,0,0,0};
    int kb = c*2 + (quad>>1);
    int sub = (quad&1)*4;
    #pragma unroll
    for (int rt = 0; rt < 4; rt++){
      float y[4];
      #pragma unroll
      for (int r = 0; r < 4; r++){
        y[r] = acc[c][rt][r] + bqa[r];
        sv[r] += y[r];
        qv[r] += y[r]*y[r];
      }
      uint2 p;
      p.x = (unsigned)rnb(y[0]) | ((unsigned)rnb(y[1])<<16);
      p.y = (unsigned)rnb(y[2]) | ((unsigned)rnb(y[3])<<16);
      *(uint2*)(Yo + ((((rtg0+rt)*8 + kb)*16 + lr)*8 + sub)) = p;
    }
    float S = hred4_sum(sv, l);
    float Q = hred4_sum(qv, l);
    if ((l & 3) == 0){
      int ch = c*16 + quad*4 + ((l>>3)&1)*2 + ((l>>2)&1);
      sred[w][ch] = S;
      sred[w][64 + ch] = Q;
    }
  }
  __syncthreads();
  if (t < 128){
    float tot = sred[0][t]+sred[1][t]+sred[2][t]+sred[3][t];
    unsafeAtomicAdd(&stats[(blockIdx.x & 7)*512 + t], tot);
  }
}

// ---- conv2: Y1 -> affine+relu -> MFMA -> Y2 + stats. W in LDS, Y prefetched ----
__global__ __launch_bounds__(256, 3) void conv2_mfma(const unsigned short* __restrict__ Yi,
    const unsigned short* __restrict__ wpk, const float* __restrict__ bias,
    const float* __restrict__ aff, unsigned short* __restrict__ Yo,
    float* __restrict__ stats){
  __shared__ float sred[4][128];
  __shared__ uint4 Wl4[512];           // 8 KB
  const unsigned short* Wl = (const unsigned short*)Wl4;
  const int t = threadIdx.x, w = t>>6, l = t&63, quad = l>>4, lr = l&15;
  const int m0 = blockIdx.x*256;
  const int Rw = m0 + w*64;
  Wl4[t] = ((const uint4*)wpk)[t];
  Wl4[256 + t] = ((const uint4*)wpk)[256 + t];
  f32x4 acc[4][4];
  #pragma unroll
  for (int c = 0; c < 4; c++)
    #pragma unroll
    for (int rt = 0; rt < 4; rt++)
      acc[c][rt] = (f32x4){0.f,0.f,0.f,0.f};
  const int rtg0 = Rw >> 4;
  // prefetch all Y loads (8 x uint4, addresses loop-invariant)
  uint4 u[2][4];
  #pragma unroll
  for (int s = 0; s < 2; s++)
    #pragma unroll
    for (int rt = 0; rt < 4; rt++)
      u[s][rt] = *(const uint4*)(Yi + (((rtg0+rt)*8 + s*4 + quad)*16 + lr)*8);
  __syncthreads();
  #pragma unroll
  for (int s = 0; s < 2; s++){
    float4 A0 = *(const float4*)(aff + s*32 + quad*8);
    float4 A1 = *(const float4*)(aff + s*32 + quad*8 + 4);
    float4 B0 = *(const float4*)(aff + 64 + s*32 + quad*8);
    float4 B1 = *(const float4*)(aff + 64 + s*32 + quad*8 + 4);
    float aA[8] = {A0.x,A0.y,A0.z,A0.w,A1.x,A1.y,A1.z,A1.w};
    float aB[8] = {B0.x,B0.y,B0.z,B0.w,B1.x,B1.y,B1.z,B1.w};
    bf16x8 wfs[4];
    #pragma unroll
    for (int c = 0; c < 4; c++)
      wfs[c] = *(const bf16x8*)(Wl + (((c*2+s)<<6) + l)*8);
    #pragma unroll
    for (int rt = 0; rt < 4; rt++){
      unsigned ua[4] = {u[s][rt].x, u[s][rt].y, u[s][rt].z, u[s][rt].w};
      bf16x8 xb;
      #pragma unroll
      for (int j = 0; j < 8; j++){
        unsigned wd = ua[j>>1];
        float yf = __uint_as_float((j&1) ? (wd & 0xFFFF0000u) : (wd << 16));
        float x = fmaxf(0.f, fmaf(yf, aA[j], aB[j]));
        xb[j] = (short)rnb(x);
      }
      #pragma unroll
      for (int c = 0; c < 4; c++)
        acc[c][rt] = __builtin_amdgcn_mfma_f32_16x16x32_bf16(wfs[c], xb, acc[c][rt], 0,0,0);
    }
  }
  #pragma unroll
  for (int c = 0; c < 4; c++){
    float4 bq = *(const float4*)(bias + c*16 + quad*4);
    float bqa[4] = {bq.x, bq.y, bq.z, bq.w};
    float sv[4] = {0,0,0,0}, qv[4] = {0,0,0,0};
    int kb = c*2 + (quad>>1);
    int sub = (quad&1)*4;
    #pragma unroll
    for (int rt = 0; rt < 4; rt++){
      float y[4];
      #pragma unroll
      for (int r = 0; r < 4; r++){
        y[r] = acc[c][rt][r] + bqa[r];
        sv[r] += y[r];
        qv[r] += y[r]*y[r];
      }
      uint2 p;
      p.x = (unsigned)rnb(y[0]) | ((unsigned)rnb(y[1])<<16);
      p.y = (unsigned)rnb(y[2]) | ((unsigned)rnb(y[3])<<16);
      *(uint2*)(Yo + ((((rtg0+rt)*8 + kb)*16 + lr)*8 + sub)) = p;
    }
    float S = hred4_sum(sv, l);
    float Q = hred4_sum(qv, l);
    if ((l & 3) == 0){
      int ch = c*16 + quad*4 + ((l>>3)&1)*2 + ((l>>2)&1);
      sred[w][ch] = S;
      sred[w][64 + ch] = Q;
    }
  }
  __syncthreads();
  if (t < 128){
    float tot = sred[0][t]+sred[1][t]+sred[2][t]+sred[3][t];
    unsafeAtomicAdd(&stats[(blockIdx.x & 7)*512 + 128 + t], tot);
  }
}

// ---- conv3: Y2 -> affine+relu -> MFMA -> K-maxpool + stats. W in LDS, Y prefetched ----
__global__ __launch_bounds__(256, 3) void conv3_mfma(const unsigned short* __restrict__ Yi,
    const unsigned short* __restrict__ wpk, const float* __restrict__ bias,
    const float* __restrict__ aff, float* __restrict__ ymax,
    float* __restrict__ stats){
  __shared__ float sred[4][256];
  __shared__ uint4 Wl4[1024];          // 16 KB
  const unsigned short* Wl = (const unsigned short*)Wl4;
  const int t = threadIdx.x, w = t>>6, l = t&63, quad = l>>4, lr = l&15;
  const int m0 = blockIdx.x*128;
  const int Rw = m0 + w*32;
  #pragma unroll
  for (int i = 0; i < 4; i++) Wl4[i*256 + t] = ((const uint4*)wpk)[i*256 + t];
  f32x4 acc[8][2];
  #pragma unroll
  for (int c = 0; c < 8; c++){
    acc[c][0] = (f32x4){0.f,0.f,0.f,0.f};
    acc[c][1] = (f32x4){0.f,0.f,0.f,0.f};
  }
  const int rtg0 = Rw >> 4;
  uint4 u[2][2];
  #pragma unroll
  for (int s = 0; s < 2; s++)
    #pragma unroll
    for (int rt = 0; rt < 2; rt++)
      u[s][rt] = *(const uint4*)(Yi + (((rtg0+rt)*8 + s*4 + quad)*16 + lr)*8);
  __syncthreads();
  #pragma unroll
  for (int s = 0; s < 2; s++){
    float4 A0 = *(const float4*)(aff + s*32 + quad*8);
    float4 A1 = *(const float4*)(aff + s*32 + quad*8 + 4);
    float4 B0 = *(const float4*)(aff + 64 + s*32 + quad*8);
    float4 B1 = *(const float4*)(aff + 64 + s*32 + quad*8 + 4);
    float aA[8] = {A0.x,A0.y,A0.z,A0.w,A1.x,A1.y,A1.z,A1.w};
    float aB[8] = {B0.x,B0.y,B0.z,B0.w,B1.x,B1.y,B1.z,B1.w};
    #pragma unroll
    for (int rt = 0; rt < 2; rt++){
      unsigned ua[4] = {u[s][rt].x, u[s][rt].y, u[s][rt].z, u[s][rt].w};
      bf16x8 xb;
      #pragma unroll
      for (int j = 0; j < 8; j++){
        unsigned wd = ua[j>>1];
        float yf = __uint_as_float((j&1) ? (wd & 0xFFFF0000u) : (wd << 16));
        float x = fmaxf(0.f, fmaf(yf, aA[j], aB[j]));
        xb[j] = (short)rnb(x);
      }
      #pragma unroll
      for (int c = 0; c < 8; c++){
        bf16x8 wfc = *(const bf16x8*)(Wl + (((c*2+s)<<6) + l)*8);
        acc[c][rt] = __builtin_amdgcn_mfma_f32_16x16x32_bf16(wfc, xb, acc[c][rt], 0,0,0);
      }
    }
  }
  const int g = Rw >> 5;
  #pragma unroll
  for (int c = 0; c < 8; c++){
    float4 bq = *(const float4*)(bias + c*16 + quad*4);
    float bqa[4] = {bq.x, bq.y, bq.z, bq.w};
    float sv[4], qv[4], mv[4];
    #pragma unroll
    for (int r = 0; r < 4; r++){
      float y0 = acc[c][0][r] + bqa[r];
      float y1 = acc[c][1][r] + bqa[r];
      sv[r] = y0 + y1;
      qv[r] = y0*y0 + y1*y1;
      mv[r] = fmaxf(y0, y1);
    }
    float S = hred4_sum(sv, l);
    float Q = hred4_sum(qv, l);
    float Mx = hred4_max(mv, l);
    if ((l & 3) == 0){
      int ch = c*16 + quad*4 + ((l>>3)&1)*2 + ((l>>2)&1);
      sred[w][ch] = S;
      sred[w][128 + ch] = Q;
      ymax[(size_t)g*128 + ch] = Mx;
    }
  }
  __syncthreads();
  {
    float tot = sred[0][t]+sred[1][t]+sred[2][t]+sred[3][t];
    unsafeAtomicAdd(&stats[(blockIdx.x & 7)*512 + 256 + t], tot);
  }
}

__global__ void bnparam_kernel(const float* __restrict__ stats, const float* __restrict__ g,
                               const float* __restrict__ bt, float* __restrict__ outAS,
                               int sOff, int qOff, int C){
  int c = threadIdx.x;
  if (c >= C) return;
  const float inv = 1.f/(float)M_;
  float S = 0.f, Q = 0.f;
  #pragma unroll
  for (int r = 0; r < 8; r++){
    S += stats[r*512 + sOff + c];
    Q += stats[r*512 + qOff + c];
  }
  float mean = S * inv;
  float var  = Q * inv - mean*mean;
  float a = g[c] * rsqrtf(var + EPS_);
  outAS[c] = a;
  outAS[C + c] = bt[c] - mean*a;
}

__global__ void final_kernel(const float* __restrict__ ymax,
                             const float* __restrict__ affb, float* __restrict__ out){
  int t = blockIdx.x*256 + threadIdx.x;
  int o = t & 127;
  float a = affb[256 + o], s = affb[384 + o];
  out[OUT_FEAT + t] = fmaxf(0.f, a*ymax[t] + s);
}

extern "C" void kernel_launch(void* const* d_in, const int* in_sizes, int n_in,
                              void* d_out, int out_size, void* d_ws, size_t ws_size,
                              hipStream_t stream) {
  const float* xyz = (const float*)d_in[0];
  const float* nrm = (const float*)d_in[1];
  const float* pts = (const float*)d_in[2];
  const int*   fps = (const int*)d_in[3];
  const float* w0  = (const float*)d_in[4];
  const float* b0  = (const float*)d_in[5];
  const float* g0  = (const float*)d_in[6];
  const float* bt0 = (const float*)d_in[7];
  const float* w1  = (const float*)d_in[8];
  const float* b1  = (const float*)d_in[9];
  const float* g1  = (const float*)d_in[10];
  const float* bt1 = (const float*)d_in[11];
  const float* w2  = (const float*)d_in[12];
  const float* b2  = (const float*)d_in[13];
  const float* g2  = (const float*)d_in[14];
  const float* bt2 = (const float*)d_in[15];
  float* out = (float*)d_out;

  char* ws = (char*)d_ws;
  float* stats = (float*)ws;                                  // 16 KB
  float* affb  = (float*)(ws + 16384);                        // 2 KB
  int*   idxb  = (int*)(ws + 20480);                          // 2 MB
  float* ymax  = (float*)(ws + 2117632);                      // 8 MB
  unsigned short* wpack = (unsigned short*)(ws + 11554816);   // 32 KB
  unsigned short* Y1 = (unsigned short*)(ws + 18878464);      // 64 MB
  unsigned short* Y2 = (unsigned short*)(ws + 85987328);      // 64 MB

  zero_stats_kernel<<<16, 256, 0, stream>>>(stats);
  meta_kernel<<<64, 256, 0, stream>>>(xyz, nrm, fps, out);
  packw_kernel<<<64, 256, 0, stream>>>(w0, w1, w2, wpack);
  knn_kernel<<<2048, 256, 0, stream>>>(xyz, fps, idxb);
  conv1_mfma<<<2048, 256, 0, stream>>>(pts, idxb, wpack, b0, Y1, stats);
  bnparam_kernel<<<1, 64, 0, stream>>>(stats, g0, bt0, affb, 0, 64, 64);
  conv2_mfma<<<2048, 256, 0, stream>>>(Y1, wpack + 4096, b1, affb, Y2, stats);
  bnparam_kernel<<<1, 64, 0, stream>>>(stats, g1, bt1, affb + 128, 128, 192, 64);
  conv3_mfma<<<4096, 256, 0, stream>>>(Y2, wpack + 8192, b2, affb + 128, ymax, stats);
  bnparam_kernel<<<1, 128, 0, stream>>>(stats, g2, bt2, affb + 256, 256, 384, 128);
  final_kernel<<<8192, 256, 0, stream>>>(ymax, affb, out);
}